// Round 1
// baseline (22950.633 us; speedup 1.0000x reference)
//
#include <hip/hip_runtime.h>
#include <hip/hip_bf16.h>

typedef unsigned short u16;
typedef unsigned int   u32;

typedef __attribute__((ext_vector_type(8))) short short8;
typedef __attribute__((ext_vector_type(4))) float f32x4;

#define TT 1024
#define HH 512
#define BB 64
#define GCOLS 8     // batch columns per group
#define NRB 32      // row-block workgroups per group
#define LDSK 520    // padded K stride in bf16 elems (breaks bank conflicts)

__device__ __forceinline__ u16 f2bf(float f) {
    union { float f; u32 u; } v; v.f = f;
    u32 u = v.u;
    return (u16)((u + 0x7FFFu + ((u >> 16) & 1u)) >> 16);
}

__device__ __forceinline__ short8 cvt8(const float4 &a, const float4 &b) {
    short8 r;
    r[0] = (short)f2bf(a.x); r[1] = (short)f2bf(a.y);
    r[2] = (short)f2bf(a.z); r[3] = (short)f2bf(a.w);
    r[4] = (short)f2bf(b.x); r[5] = (short)f2bf(b.y);
    r[6] = (short)f2bf(b.z); r[7] = (short)f2bf(b.w);
    return r;
}

__global__ void lstm_prep(u32* cnt, u16* htbuf) {
    int i = blockIdx.x * 256 + threadIdx.x;
    if (i < 256) cnt[i] = 0;
    if (i < 8 * 2 * 8 * 512) htbuf[i] = 0;
}

__global__ __launch_bounds__(256, 1)
void lstm_persist(const float* __restrict__ in_seq,
                  const float* __restrict__ Wxi, const float* __restrict__ Wxf,
                  const float* __restrict__ Wxo, const float* __restrict__ Wxg,
                  const float* __restrict__ Whi, const float* __restrict__ Whf,
                  const float* __restrict__ Who, const float* __restrict__ Whg,
                  float* __restrict__ out, u32* cnt, u16* htbuf)
{
    // LDS: B-operand staging, [col(16, 8 used)][K padded] bf16
    __shared__ u16 xt[16][LDSK];
    __shared__ u16 htl[16][LDSK];
    __shared__ float gates[4][16][8];

    const int tid  = threadIdx.x;
    const int bid  = blockIdx.x;
    const int g    = bid & 7;    // column group (XCD-aligned under round-robin dispatch)
    const int rblk = bid >> 3;   // row block: hidden rows [16*rblk, 16*rblk+16)
    const int wave = tid >> 6;   // wave 0..3 -> gates i,f,o,g
    const int lane = tid & 63;
    const int lrow = lane & 15;          // A row / B col within 16x16 tile
    const int lk8  = (lane >> 4) * 8;    // K sub-offset

    // zero LDS once (cols 8..15 stay zero forever -> zero-padded MFMA B)
    {
        u16* p0 = &xt[0][0]; u16* p1 = &htl[0][0];
        for (int i = tid; i < 16 * LDSK; i += 256) { p0[i] = 0; p1[i] = 0; }
    }

    const float* Wx = (wave == 0) ? Wxi : (wave == 1) ? Wxf : (wave == 2) ? Wxo : Wxg;
    const float* Wh = (wave == 0) ? Whi : (wave == 1) ? Whf : (wave == 2) ? Who : Whg;

    // A fragments (weights) resident in VGPRs for the whole kernel: 128 VGPRs/lane
    short8 afrag[32];
    const int grow = rblk * 16 + lrow;
    #pragma unroll
    for (int kk = 0; kk < 16; ++kk) {
        const float* s = Wx + grow * HH + kk * 32 + lk8;
        afrag[kk] = cvt8(*(const float4*)s, *(const float4*)(s + 4));
    }
    #pragma unroll
    for (int kk = 0; kk < 16; ++kk) {
        const float* s = Wh + grow * HH + kk * 32 + lk8;
        afrag[16 + kk] = cvt8(*(const float4*)s, *(const float4*)(s + 4));
    }

    u32* mycnt = cnt + g * 16;                    // 64B-separated counters
    u16* htb0  = htbuf + (g * 2) * (8 * 512);     // per-group double-buffered h (bf16)

    float cst = 0.f;                              // persistent c state (tid<128)
    const int hr  = (tid & 127) >> 3;
    const int col = tid & 7;
    const int hid = rblk * 16 + hr;

    __syncthreads();

    for (int t = 0; t < TT; ++t) {
        // ---- prefetch x_t slice into registers (independent of barrier) ----
        float xv[16];
        const float* xb = in_seq + (size_t)t * (HH * BB) + g * GCOLS;
        #pragma unroll
        for (int e = 0; e < 16; ++e) {
            int lin = e * 256 + tid;
            xv[e] = xb[(lin >> 3) * BB + (lin & 7)];
        }

        // ---- wait for all 32 row-blocks of this group to finish step t-1 ----
        if (t > 0) {
            u32 target = (u32)(NRB * t);
            while (__hip_atomic_load(mycnt, __ATOMIC_ACQUIRE, __HIP_MEMORY_SCOPE_AGENT) < target)
                __builtin_amdgcn_s_sleep(1);
        }

        // ---- copy group h state (bf16, [col][hid]) into LDS ----
        {
            const u16* src = htb0 + (t & 1) * (8 * 512) + tid * 16;
            uint4 v0 = *(const uint4*)(src);
            uint4 v1 = *(const uint4*)(src + 8);
            int c = tid >> 5, k0 = (tid & 31) * 16;
            *(uint4*)&htl[c][k0]     = v0;
            *(uint4*)&htl[c][k0 + 8] = v1;
        }

        // ---- x -> LDS bf16, [col][k] ----
        #pragma unroll
        for (int e = 0; e < 16; ++e) {
            int lin = e * 256 + tid;
            xt[lin & 7][lin >> 3] = f2bf(xv[e]);
        }
        __syncthreads();

        // ---- gate pre-activations: [16 rows x 16 cols] = W[16 x 1024] @ [x;h][1024 x 16] ----
        f32x4 acc = {0.f, 0.f, 0.f, 0.f};
        #pragma unroll
        for (int kk = 0; kk < 16; ++kk) {
            short8 bfr = *(const short8*)&xt[lrow][kk * 32 + lk8];
            acc = __builtin_amdgcn_mfma_f32_16x16x32_bf16(afrag[kk], bfr, acc, 0, 0, 0);
        }
        #pragma unroll
        for (int kk = 0; kk < 16; ++kk) {
            short8 bfr = *(const short8*)&htl[lrow][kk * 32 + lk8];
            acc = __builtin_amdgcn_mfma_f32_16x16x32_bf16(afrag[16 + kk], bfr, acc, 0, 0, 0);
        }
        // C/D layout: col = lane&15, row = (lane>>4)*4 + reg   [verified m89/m91]
        if (lrow < 8) {
            #pragma unroll
            for (int r = 0; r < 4; ++r)
                gates[wave][(lane >> 4) * 4 + r][lrow] = acc[r];
        }
        __syncthreads();

        // ---- elementwise LSTM cell update; c persistent in registers ----
        if (tid < 128) {
            float ip = gates[0][hr][col];
            float fp = gates[1][hr][col];
            float op = gates[2][hr][col];
            float gp = gates[3][hr][col];
            float iv = 1.f / (1.f + __expf(-ip));
            float fv = 1.f / (1.f + __expf(-fp));
            float ov = 1.f / (1.f + __expf(-op));
            float gv = tanhf(gp);
            cst = fv * cst + iv * gv;
            float hv = ov * tanhf(cst);
            out[(size_t)t * (HH * BB) + hid * BB + g * GCOLS + col] = hv;
            htb0[((t + 1) & 1) * (8 * 512) + col * 512 + hid] = f2bf(hv);
            if (t == TT - 1) {
                size_t base = (size_t)TT * HH * BB;
                out[base + hid * BB + g * GCOLS + col] = hv;            // final h
                out[base + HH * BB + hid * BB + g * GCOLS + col] = cst; // final c
            }
        }

        // ---- release-arrive ----
        __syncthreads();
        if (tid == 0)
            __hip_atomic_fetch_add(mycnt, 1u, __ATOMIC_RELEASE, __HIP_MEMORY_SCOPE_AGENT);
    }
}

extern "C" void kernel_launch(void* const* d_in, const int* in_sizes, int n_in,
                              void* d_out, int out_size, void* d_ws, size_t ws_size,
                              hipStream_t stream)
{
    const float* in_seq = (const float*)d_in[0];
    const float* Wxi = (const float*)d_in[1];
    const float* Wxf = (const float*)d_in[2];
    const float* Wxo = (const float*)d_in[3];
    const float* Wxg = (const float*)d_in[4];
    const float* Whi = (const float*)d_in[5];
    const float* Whf = (const float*)d_in[6];
    const float* Who = (const float*)d_in[7];
    const float* Whg = (const float*)d_in[8];

    u32* cnt   = (u32*)d_ws;
    u16* htbuf = (u16*)((char*)d_ws + 1024);

    lstm_prep<<<256, 256, 0, stream>>>(cnt, htbuf);
    lstm_persist<<<256, 256, 0, stream>>>(in_seq, Wxi, Wxf, Wxo, Wxg,
                                          Whi, Whf, Who, Whg,
                                          (float*)d_out, cnt, htbuf);
}

// Round 2
// 3387.306 us; speedup vs baseline: 6.7755x; 6.7755x over previous
//
#include <hip/hip_runtime.h>
#include <hip/hip_bf16.h>

typedef unsigned short u16;
typedef unsigned int   u32;
typedef unsigned long long u64;

typedef __attribute__((ext_vector_type(8))) short short8;
typedef __attribute__((ext_vector_type(4))) float f32x4;

#define TT 1024
#define HH 512
#define BB 64
#define GCOLS 8     // batch columns per group
#define NRB 32      // row-block workgroups per group
#define LDSK 520    // padded K stride in bf16 elems

__device__ __forceinline__ u16 f2bf(float f) {
    union { float f; u32 u; } v; v.f = f;
    u32 u = v.u;
    return (u16)((u + 0x7FFFu + ((u >> 16) & 1u)) >> 16);
}

__device__ __forceinline__ short8 cvt8(const float4 &a, const float4 &b) {
    short8 r;
    r[0] = (short)f2bf(a.x); r[1] = (short)f2bf(a.y);
    r[2] = (short)f2bf(a.z); r[3] = (short)f2bf(a.w);
    r[4] = (short)f2bf(b.x); r[5] = (short)f2bf(b.y);
    r[6] = (short)f2bf(b.z); r[7] = (short)f2bf(b.w);
    return r;
}

__global__ void lstm_prep(u32* cnt) {
    // zero counters with agent-scope (LLC-visible) stores
    __hip_atomic_store(&cnt[threadIdx.x], 0u, __ATOMIC_RELAXED, __HIP_MEMORY_SCOPE_AGENT);
}

__global__ __launch_bounds__(256, 1)
void lstm_persist(const float* __restrict__ in_seq,
                  const float* __restrict__ Wxi, const float* __restrict__ Wxf,
                  const float* __restrict__ Wxo, const float* __restrict__ Wxg,
                  const float* __restrict__ Whi, const float* __restrict__ Whf,
                  const float* __restrict__ Who, const float* __restrict__ Whg,
                  float* __restrict__ out, u32* cnt, u16* htbuf)
{
    __shared__ u16 xt[16][LDSK];    // B operand (x half), [col][k], cols 8..15 stay zero
    __shared__ u16 htl[16][LDSK];   // B operand (h half)
    __shared__ float gates[4][16][8];

    const int tid  = threadIdx.x;
    const int bid  = blockIdx.x;
    const int g    = bid & 7;    // column group
    const int rblk = bid >> 3;   // row block: hidden rows [16*rblk, 16*rblk+16)
    const int wave = tid >> 6;   // gate i,f,o,g
    const int lane = tid & 63;
    const int lrow = lane & 15;
    const int lk8  = (lane >> 4) * 8;

    // zero LDS once
    {
        u16* p0 = &xt[0][0]; u16* p1 = &htl[0][0];
        for (int i = tid; i < 16 * LDSK; i += 256) { p0[i] = 0; p1[i] = 0; }
    }

    const float* Wx = (wave == 0) ? Wxi : (wave == 1) ? Wxf : (wave == 2) ? Wxo : Wxg;
    const float* Wh = (wave == 0) ? Whi : (wave == 1) ? Whf : (wave == 2) ? Who : Whg;

    // weights resident in VGPRs (128 VGPRs/lane)
    short8 afrag[32];
    const int grow = rblk * 16 + lrow;
    #pragma unroll
    for (int kk = 0; kk < 16; ++kk) {
        const float* s = Wx + grow * HH + kk * 32 + lk8;
        afrag[kk] = cvt8(*(const float4*)s, *(const float4*)(s + 4));
    }
    #pragma unroll
    for (int kk = 0; kk < 16; ++kk) {
        const float* s = Wh + grow * HH + kk * 32 + lk8;
        afrag[16 + kk] = cvt8(*(const float4*)s, *(const float4*)(s + 4));
    }

    u32* mycnt = cnt + g * 16;                 // 64B-separated per-group counters
    u16* htb0  = htbuf + (g * 2) * (8 * 512);  // per-group double-buffered h (bf16), [buf][col][hid]

    float cst = 0.f;
    const int hr  = (tid & 127) >> 3;
    const int col = tid & 7;
    const int hid = rblk * 16 + hr;

    // prefetch x_0
    float xv[16];
    {
        const float* xb = in_seq + g * GCOLS;
        #pragma unroll
        for (int e = 0; e < 16; ++e) {
            int lin = e * 256 + tid;
            xv[e] = xb[(lin >> 3) * BB + (lin & 7)];
        }
    }

    __syncthreads();

    for (int t = 0; t < TT; ++t) {
        // ---- stage x_t -> LDS bf16 [col][k] ----
        #pragma unroll
        for (int e = 0; e < 16; ++e) {
            int lin = e * 256 + tid;
            xt[lin & 7][lin >> 3] = f2bf(xv[e]);
        }
        __syncthreads();  // B1

        // ---- prefetch x_{t+1} (independent; overlaps everything below) ----
        if (t + 1 < TT) {
            const float* xb = in_seq + (size_t)(t + 1) * (HH * BB) + g * GCOLS;
            #pragma unroll
            for (int e = 0; e < 16; ++e) {
                int lin = e * 256 + tid;
                xv[e] = xb[(lin >> 3) * BB + (lin & 7)];
            }
        }

        // ---- x-half MFMAs (no dependence on h: do them before the poll) ----
        f32x4 acc = {0.f, 0.f, 0.f, 0.f};
        #pragma unroll
        for (int kk = 0; kk < 16; ++kk) {
            short8 bfr = *(const short8*)&xt[lrow][kk * 32 + lk8];
            acc = __builtin_amdgcn_mfma_f32_16x16x32_bf16(afrag[kk], bfr, acc, 0, 0, 0);
        }

        // ---- wait for all 32 row-blocks of this group to finish step t-1 ----
        if (t > 0) {
            u32 target = (u32)(NRB * t);
            while (__hip_atomic_load(mycnt, __ATOMIC_RELAXED, __HIP_MEMORY_SCOPE_AGENT) < target)
                __builtin_amdgcn_s_sleep(1);
            asm volatile("" ::: "memory");

            // ---- group h state -> LDS (LLC-bypass loads; 32B/thread) ----
            const u64* src = (const u64*)(htb0 + (t & 1) * (8 * 512)) + tid * 4;
            u64 a0 = __hip_atomic_load(src + 0, __ATOMIC_RELAXED, __HIP_MEMORY_SCOPE_AGENT);
            u64 a1 = __hip_atomic_load(src + 1, __ATOMIC_RELAXED, __HIP_MEMORY_SCOPE_AGENT);
            u64 a2 = __hip_atomic_load(src + 2, __ATOMIC_RELAXED, __HIP_MEMORY_SCOPE_AGENT);
            u64 a3 = __hip_atomic_load(src + 3, __ATOMIC_RELAXED, __HIP_MEMORY_SCOPE_AGENT);
            int c = tid >> 5, k0 = (tid & 31) * 16;
            u64* dst = (u64*)&htl[c][k0];
            dst[0] = a0; dst[1] = a1; dst[2] = a2; dst[3] = a3;
        }
        __syncthreads();  // B2

        // ---- h-half MFMAs ----
        #pragma unroll
        for (int kk = 0; kk < 16; ++kk) {
            short8 bfr = *(const short8*)&htl[lrow][kk * 32 + lk8];
            acc = __builtin_amdgcn_mfma_f32_16x16x32_bf16(afrag[16 + kk], bfr, acc, 0, 0, 0);
        }
        // C/D layout: col = lane&15, row = (lane>>4)*4 + reg
        if (lrow < 8) {
            #pragma unroll
            for (int r = 0; r < 4; ++r)
                gates[wave][(lane >> 4) * 4 + r][lrow] = acc[r];
        }
        __syncthreads();  // B3

        // ---- elementwise cell update (c persistent in registers) ----
        if (tid < 128) {
            float ip = gates[0][hr][col];
            float fp = gates[1][hr][col];
            float op = gates[2][hr][col];
            float gp = gates[3][hr][col];
            float iv = 1.f / (1.f + __expf(-ip));
            float fv = 1.f / (1.f + __expf(-fp));
            float ov = 1.f / (1.f + __expf(-op));
            float gv = tanhf(gp);
            cst = fv * cst + iv * gv;
            float hv = ov * tanhf(cst);
            out[(size_t)t * (HH * BB) + hid * BB + g * GCOLS + col] = hv;

            // pack 2 adjacent h rows into one u32, store LLC-bypass
            u16 hb = f2bf(hv);
            u32 up = (u32)(u16)__shfl_down((int)(u32)hb, 8);
            if (((lane >> 3) & 1) == 0) {
                u32 v = (u32)hb | (up << 16);
                u32* dptr = (u32*)(htb0 + ((t + 1) & 1) * (8 * 512) + col * 512 + hid);
                __hip_atomic_store(dptr, v, __ATOMIC_RELAXED, __HIP_MEMORY_SCOPE_AGENT);
            }
            if (t == TT - 1) {
                size_t base = (size_t)TT * HH * BB;
                out[base + hid * BB + g * GCOLS + col] = hv;
                out[base + HH * BB + hid * BB + g * GCOLS + col] = cst;
            }
            // drain this wave's h stores to LLC before the flag add
            asm volatile("s_waitcnt vmcnt(0)" ::: "memory");
        }
        __syncthreads();  // B4
        if (tid == 0)
            __hip_atomic_fetch_add(mycnt, 1u, __ATOMIC_RELAXED, __HIP_MEMORY_SCOPE_AGENT);
    }
}

extern "C" void kernel_launch(void* const* d_in, const int* in_sizes, int n_in,
                              void* d_out, int out_size, void* d_ws, size_t ws_size,
                              hipStream_t stream)
{
    const float* in_seq = (const float*)d_in[0];
    const float* Wxi = (const float*)d_in[1];
    const float* Wxf = (const float*)d_in[2];
    const float* Wxo = (const float*)d_in[3];
    const float* Wxg = (const float*)d_in[4];
    const float* Whi = (const float*)d_in[5];
    const float* Whf = (const float*)d_in[6];
    const float* Who = (const float*)d_in[7];
    const float* Whg = (const float*)d_in[8];

    u32* cnt   = (u32*)d_ws;
    u16* htbuf = (u16*)((char*)d_ws + 1024);

    lstm_prep<<<1, 256, 0, stream>>>(cnt);
    lstm_persist<<<256, 256, 0, stream>>>(in_seq, Wxi, Wxf, Wxo, Wxg,
                                          Whi, Whf, Who, Whg,
                                          (float*)d_out, cnt, htbuf);
}